// Round 11
// baseline (239.002 us; speedup 1.0000x reference)
//
#include <hip/hip_runtime.h>
#include <hip/hip_fp16.h>

#define N_NODES 65536
#define N_FEAT  64
#define N_HEADS 4
#define BATCHSZ 131072
#define ALPHA   0.2f
#define SRC_PER_NODE 8   // (BATCHSZ*4)/N_NODES, guaranteed by construction
#define NSLICE   4       // feature slices; slice = blockIdx & 3 -> XCD-affine (perf heuristic only)
#define SLICE_F  16      // feats per slice; 16 f32 out = one 64B line per (head,slice) store

typedef float f32x2 __attribute__((ext_vector_type(2)));

// ROCm fp16 header lacks __hmax2; component-wise max (lowers to packed/2x v_max_f16)
__device__ __forceinline__ __half2 h2max(__half2 a, __half2 b) {
    __half2 r;
    r.x = __hmax(a.x, b.x);
    r.y = __hmax(a.y, b.y);
    return r;
}

// ---- Pass 0: feat f32 row-major -> fp16 slice-major [NSLICE][N_NODES][SLICE_F]
// Per-XCD gather working set becomes 2 MB/slice (fits 4 MB L2).
__global__ __launch_bounds__(256) void to_half_sliced(const float* __restrict__ feat,
                                                      __half* __restrict__ feat_s) {
    int i = (blockIdx.x * 256 + threadIdx.x) * 8;   // flat f32 index
    int n   = i >> 6;        // node
    int f0  = i & 63;        // 0,8,...,56
    int s   = f0 >> 4;       // slice
    int off = f0 & 15;       // 0 or 8 within slice
    float4 a = *(const float4*)(feat + i);
    float4 b = *(const float4*)(feat + i + 4);
    uint4 o;
    o.x = __builtin_bit_cast(unsigned int, __floats2half2_rn(a.x, a.y));
    o.y = __builtin_bit_cast(unsigned int, __floats2half2_rn(a.z, a.w));
    o.z = __builtin_bit_cast(unsigned int, __floats2half2_rn(b.x, b.y));
    o.w = __builtin_bit_cast(unsigned int, __floats2half2_rn(b.z, b.w));
    *(uint4*)(feat_s + (s * N_NODES + n) * SLICE_F + off) = o;
}

// ---- Pass 1: inverse index with packed neighbor IDs (unchanged from R9) ----
__global__ __launch_bounds__(256) void build_index(const int* __restrict__ batch,
                                                   int* __restrict__ cnt,
                                                   int2* __restrict__ idx2) {
    int b = blockIdx.x * blockDim.x + threadIdx.x;  // 0 .. BATCHSZ-1
    int4 br = ((const int4*)batch)[b];
    int p0 = atomicAdd(&cnt[br.x], 1);
    int p1 = atomicAdd(&cnt[br.y], 1);
    int p2 = atomicAdd(&cnt[br.z], 1);
    int p3 = atomicAdd(&cnt[br.w], 1);
    if (p0 < SRC_PER_NODE) idx2[br.x * SRC_PER_NODE + p0] = make_int2(br.y | (br.z << 16), br.w);
    if (p1 < SRC_PER_NODE) idx2[br.y * SRC_PER_NODE + p1] = make_int2(br.x | (br.z << 16), br.w);
    if (p2 < SRC_PER_NODE) idx2[br.z * SRC_PER_NODE + p2] = make_int2(br.x | (br.y << 16), br.w);
    if (p3 < SRC_PER_NODE) idx2[br.w * SRC_PER_NODE + p3] = make_int2(br.x | (br.y << 16), br.z);
}

// ---- Pass 2: sliced gather + half2 mix/max + epilogue ----------------------
// Block = 4 waves = 4 nodes x 1 slice; slice = blockIdx & 3 (XCD-affine).
// Lane = src*8 + fp: src = lane>>3 covers one of the 8 sources, fp = lane&7
// covers feature pair 2*fp within the slice. Mix+max fully in packed fp16;
// butterfly over the src dimension (xor 8,16,32); lanes<32 store one 64B
// line per head: out[t*256 + a*64 + slice*16 + 2*fp] (float2, nontemporal).
__global__ __launch_bounds__(256) void gat_agg_sliced(const __half* __restrict__ feat_s,
                                                      const float* __restrict__ att,
                                                      const int2* __restrict__ idx2,
                                                      float* __restrict__ out) {
    const int wave  = threadIdx.x >> 6;
    const int lane  = threadIdx.x & 63;
    const int src   = lane >> 3;
    const int fp    = lane & 7;
    const int slice = blockIdx.x & 3;
    const int t     = (blockIdx.x >> 2) * 4 + wave;

    // attention weights -> replicated half2
    __half2 w2[N_HEADS][3];
    #pragma unroll
    for (int a = 0; a < N_HEADS; ++a)
        #pragma unroll
        for (int k = 0; k < 3; ++k)
            w2[a][k] = __float2half2_rn(att[a * 3 + k]);

    // this lane's source: packed neighbor triple (8-lane broadcast, 64B/wave)
    int2 nb = idx2[t * SRC_PER_NODE + src];
    int n0 = nb.x & 0xffff;
    int n1 = ((unsigned)nb.x) >> 16;
    int n2 = nb.y & 0xffff;

    const __half* plane = feat_s + slice * (N_NODES * SLICE_F);

    __half2 f0 = __builtin_bit_cast(__half2, *(const unsigned int*)(plane + n0 * SLICE_F + 2 * fp));
    __half2 f1 = __builtin_bit_cast(__half2, *(const unsigned int*)(plane + n1 * SLICE_F + 2 * fp));
    __half2 f2 = __builtin_bit_cast(__half2, *(const unsigned int*)(plane + n2 * SLICE_F + 2 * fp));

    // head mixes for this (src, feature-pair): packed fp16
    __half2 v0 = __hfma2(w2[0][0], f0, __hfma2(w2[0][1], f1, __hmul2(w2[0][2], f2)));
    __half2 v1 = __hfma2(w2[1][0], f0, __hfma2(w2[1][1], f1, __hmul2(w2[1][2], f2)));
    __half2 v2 = __hfma2(w2[2][0], f0, __hfma2(w2[2][1], f1, __hmul2(w2[2][2], f2)));
    __half2 v3 = __hfma2(w2[3][0], f0, __hfma2(w2[3][1], f1, __hmul2(w2[3][2], f2)));

    // max over the 8 sources: butterfly on lane bits 3,4,5 (src dimension)
    #define BFLY(V) {                                                              \
        V = h2max(V, __builtin_bit_cast(__half2, __shfl_xor(__builtin_bit_cast(int, V),  8))); \
        V = h2max(V, __builtin_bit_cast(__half2, __shfl_xor(__builtin_bit_cast(int, V), 16))); \
        V = h2max(V, __builtin_bit_cast(__half2, __shfl_xor(__builtin_bit_cast(int, V), 32))); \
    }
    BFLY(v0); BFLY(v1); BFLY(v2); BFLY(v3);
    #undef BFLY

    // epilogue: lanes 0-31, lane = a*8 + fp; one 64B line per head per wave
    if (lane < 32) {
        int a = lane >> 3;            // head  (fp = lane&7 preserved)
        __half2 mv = (a < 2) ? ((a == 0) ? v0 : v1) : ((a == 2) ? v2 : v3);
        float2 mf = __half22float2(mv);
        float2 fs = __half22float2(__builtin_bit_cast(__half2,
                        *(const unsigned int*)(plane + t * SLICE_F + 2 * fp)));
        float ox = fs.x + mf.x; ox = fmaxf(ox, ALPHA * ox);
        float oy = fs.y + mf.y; oy = fmaxf(oy, ALPHA * oy);
        f32x2 ov = {ox, oy};
        __builtin_nontemporal_store(ov,
            (f32x2*)(out + t * (N_HEADS * N_FEAT) + a * N_FEAT + slice * SLICE_F + 2 * fp));
    }
}

extern "C" void kernel_launch(void* const* d_in, const int* in_sizes, int n_in,
                              void* d_out, int out_size, void* d_ws, size_t ws_size,
                              hipStream_t stream) {
    const int*   batch = (const int*)d_in[0];    // [BATCHSZ, 4] int32
    const float* feat  = (const float*)d_in[1];  // [N_NODES, N_FEAT] f32
    const float* att   = (const float*)d_in[2];  // [N_HEADS, 3] f32
    float* out = (float*)d_out;                  // [N_NODES, 256] f32

    char* ws = (char*)d_ws;
    int*    cnt    = (int*)ws;                                        // 256 KB
    int2*   idx2   = (int2*)(ws + N_NODES * sizeof(int));             // 4 MB
    __half* feat_s = (__half*)(ws + N_NODES * sizeof(int)
                                  + N_NODES * SRC_PER_NODE * sizeof(int2));  // 8 MB

    hipMemsetAsync(cnt, 0, N_NODES * sizeof(int), stream);
    to_half_sliced<<<(N_NODES * N_FEAT) / (256 * 8), 256, 0, stream>>>(feat, feat_s);
    build_index<<<BATCHSZ / 256, 256, 0, stream>>>(batch, cnt, idx2);
    gat_agg_sliced<<<(N_NODES / 4) * NSLICE, 256, 0, stream>>>(feat_s, att, idx2, out);
}

// Round 12
// 157.536 us; speedup vs baseline: 1.5171x; 1.5171x over previous
//
#include <hip/hip_runtime.h>
#include <hip/hip_fp16.h>

#define N_NODES 65536
#define N_FEAT  64
#define N_HEADS 4
#define BATCHSZ 131072
#define ALPHA   0.2f
#define SRC_PER_NODE 8   // (BATCHSZ*4)/N_NODES, guaranteed by construction
#define NSLICE   4       // slice = blockIdx&3 -> XCD-affine (2MB/slice fits 4MB L2); perf-only
#define SLICE_F  16      // halfs per slice

#define PREP_TOHALF_BLOCKS ((N_NODES * N_FEAT) / (256 * 8))   // 2048
#define PREP_BUILD_BLOCKS  (BATCHSZ / 256)                    // 512

typedef float f32x2 __attribute__((ext_vector_type(2)));

// ROCm fp16 header lacks __hmax2; component-wise (lowers to v_pk_max_f16 / 2x v_max_f16)
__device__ __forceinline__ __half2 h2max(__half2 a, __half2 b) {
    __half2 r;
    r.x = __hmax(a.x, b.x);
    r.y = __hmax(a.y, b.y);
    return r;
}

// ---- Pass 1 (fused): feat f32 -> fp16 slice-major [NSLICE][N_NODES][SLICE_F]
//                      + inverse index with packed neighbor IDs
__global__ __launch_bounds__(256) void prep(const float* __restrict__ feat,
                                            __half* __restrict__ feat_s,
                                            const int* __restrict__ batch,
                                            int* __restrict__ cnt,
                                            int2* __restrict__ idx2) {
    if (blockIdx.x < PREP_TOHALF_BLOCKS) {
        int i = (blockIdx.x * 256 + threadIdx.x) * 8;   // flat f32 index
        int n   = i >> 6;        // node
        int f0  = i & 63;
        int s   = f0 >> 4;       // slice
        int off = f0 & 15;       // 0 or 8 within slice
        float4 a = *(const float4*)(feat + i);
        float4 b = *(const float4*)(feat + i + 4);
        uint4 o;
        o.x = __builtin_bit_cast(unsigned int, __floats2half2_rn(a.x, a.y));
        o.y = __builtin_bit_cast(unsigned int, __floats2half2_rn(a.z, a.w));
        o.z = __builtin_bit_cast(unsigned int, __floats2half2_rn(b.x, b.y));
        o.w = __builtin_bit_cast(unsigned int, __floats2half2_rn(b.z, b.w));
        *(uint4*)(feat_s + (s * N_NODES + n) * SLICE_F + off) = o;
    } else {
        int b = (blockIdx.x - PREP_TOHALF_BLOCKS) * 256 + threadIdx.x;  // 0..BATCHSZ-1
        int4 br = ((const int4*)batch)[b];
        int p0 = atomicAdd(&cnt[br.x], 1);
        int p1 = atomicAdd(&cnt[br.y], 1);
        int p2 = atomicAdd(&cnt[br.z], 1);
        int p3 = atomicAdd(&cnt[br.w], 1);
        if (p0 < SRC_PER_NODE) idx2[br.x * SRC_PER_NODE + p0] = make_int2(br.y | (br.z << 16), br.w);
        if (p1 < SRC_PER_NODE) idx2[br.y * SRC_PER_NODE + p1] = make_int2(br.x | (br.z << 16), br.w);
        if (p2 < SRC_PER_NODE) idx2[br.z * SRC_PER_NODE + p2] = make_int2(br.x | (br.y << 16), br.w);
        if (p3 < SRC_PER_NODE) idx2[br.w * SRC_PER_NODE + p3] = make_int2(br.x | (br.y << 16), br.z);
    }
}

// ---- Pass 2: sliced gather, serial over sources, ZERO shuffles -------------
// Block = 4 waves; wave = 8 node-slices (grp = lane>>3 picks node, fp = lane&7
// picks half2 position in the 16-half slice). slice = blockIdx & 3 (XCD-affine).
// Each lane loops the node's 8 sources: 3 gathered dwords + 4 packed FMA-triples
// + 4 packed max; running maxima stay in registers. Epilogue: fp16 self + max,
// f32 leaky-relu, 4x nontemporal float2 stores (each 8-lane group = 64B line).
__global__ __launch_bounds__(256) void gat_agg_serial(const __half* __restrict__ feat_s,
                                                      const float* __restrict__ att,
                                                      const int2* __restrict__ idx2,
                                                      float* __restrict__ out) {
    const int lane  = threadIdx.x & 63;
    const int wave  = threadIdx.x >> 6;
    const int grp   = lane >> 3;    // node within this wave's 8
    const int fp    = lane & 7;     // half2 position (feats 2*fp, 2*fp+1 of slice)
    const int slice = blockIdx.x & 3;
    const int t     = (blockIdx.x >> 2) * 32 + wave * 8 + grp;

    const __half* plane = feat_s + (size_t)slice * (N_NODES * SLICE_F);

    __half2 w2[N_HEADS][3];
    #pragma unroll
    for (int a = 0; a < N_HEADS; ++a)
        #pragma unroll
        for (int k = 0; k < 3; ++k)
            w2[a][k] = __float2half2_rn(att[a * 3 + k]);

    const __half2 ninf = __float2half2_rn(-INFINITY);
    __half2 m0 = ninf, m1 = ninf, m2 = ninf, m3 = ninf;

    const int2* ip = idx2 + t * SRC_PER_NODE;
    #pragma unroll
    for (int s = 0; s < SRC_PER_NODE; ++s) {
        int2 nb = ip[s];                       // 64B/wave broadcast (8 groups x 8B)
        int n0 = nb.x & 0xffff;
        int n1 = ((unsigned)nb.x) >> 16;
        int n2 = nb.y & 0xffff;
        __half2 f0 = __builtin_bit_cast(__half2, *(const unsigned int*)(plane + n0 * SLICE_F + 2 * fp));
        __half2 f1 = __builtin_bit_cast(__half2, *(const unsigned int*)(plane + n1 * SLICE_F + 2 * fp));
        __half2 f2 = __builtin_bit_cast(__half2, *(const unsigned int*)(plane + n2 * SLICE_F + 2 * fp));
        m0 = h2max(m0, __hfma2(w2[0][0], f0, __hfma2(w2[0][1], f1, __hmul2(w2[0][2], f2))));
        m1 = h2max(m1, __hfma2(w2[1][0], f0, __hfma2(w2[1][1], f1, __hmul2(w2[1][2], f2))));
        m2 = h2max(m2, __hfma2(w2[2][0], f0, __hfma2(w2[2][1], f1, __hmul2(w2[2][2], f2))));
        m3 = h2max(m3, __hfma2(w2[3][0], f0, __hfma2(w2[3][1], f1, __hmul2(w2[3][2], f2))));
    }

    float2 sf = __half22float2(__builtin_bit_cast(__half2,
                    *(const unsigned int*)(plane + t * SLICE_F + 2 * fp)));
    float* obase = out + (size_t)t * (N_HEADS * N_FEAT) + slice * SLICE_F + 2 * fp;

    #define EMIT(A, MV) {                                                    \
        float2 mf = __half22float2(MV);                                      \
        float ox = sf.x + mf.x; ox = fmaxf(ox, ALPHA * ox);                  \
        float oy = sf.y + mf.y; oy = fmaxf(oy, ALPHA * oy);                  \
        f32x2 ov = {ox, oy};                                                 \
        __builtin_nontemporal_store(ov, (f32x2*)(obase + (A) * N_FEAT));     \
    }
    EMIT(0, m0); EMIT(1, m1); EMIT(2, m2); EMIT(3, m3);
    #undef EMIT
}

extern "C" void kernel_launch(void* const* d_in, const int* in_sizes, int n_in,
                              void* d_out, int out_size, void* d_ws, size_t ws_size,
                              hipStream_t stream) {
    const int*   batch = (const int*)d_in[0];    // [BATCHSZ, 4] int32
    const float* feat  = (const float*)d_in[1];  // [N_NODES, N_FEAT] f32
    const float* att   = (const float*)d_in[2];  // [N_HEADS, 3] f32
    float* out = (float*)d_out;                  // [N_NODES, 256] f32

    char* ws = (char*)d_ws;
    int*    cnt    = (int*)ws;                                        // 256 KB
    int2*   idx2   = (int2*)(ws + N_NODES * sizeof(int));             // 4 MB
    __half* feat_s = (__half*)(ws + N_NODES * sizeof(int)
                                  + N_NODES * SRC_PER_NODE * sizeof(int2));  // 8 MB

    hipMemsetAsync(cnt, 0, N_NODES * sizeof(int), stream);
    prep<<<PREP_TOHALF_BLOCKS + PREP_BUILD_BLOCKS, 256, 0, stream>>>(feat, feat_s, batch, cnt, idx2);
    gat_agg_serial<<<(N_NODES / 32) * NSLICE, 256, 0, stream>>>(feat_s, att, idx2, out);
}

// Round 14
// 149.440 us; speedup vs baseline: 1.5993x; 1.0542x over previous
//
#include <hip/hip_runtime.h>
#include <hip/hip_fp16.h>

#define N_NODES 65536
#define N_FEAT  64
#define N_HEADS 4
#define BATCHSZ 131072
#define ALPHA   0.2f
#define SRC_PER_NODE 8   // (BATCHSZ*4)/N_NODES, guaranteed by construction
#define NSLICE   4       // slice = blockIdx&3 -> XCD-affine (2MB/slice fits 4MB L2); perf-only
#define SLICE_F  16      // halfs per slice row

#define PREP_TOHALF_BLOCKS ((N_NODES * N_FEAT) / (256 * 8))   // 2048
#define PREP_BUILD_BLOCKS  (BATCHSZ / 256)                    // 512

typedef _Float16 h8   __attribute__((ext_vector_type(8)));   // 4 VGPR, ops lower to v_pk_*_f16
typedef float    f32x4 __attribute__((ext_vector_type(4)));
typedef float    f32x8 __attribute__((ext_vector_type(8)));

// ---- Pass 1 (fused): feat f32 -> fp16 slice-major [NSLICE][N_NODES][SLICE_F]
//                      + inverse index with packed neighbor IDs
__global__ __launch_bounds__(256) void prep(const float* __restrict__ feat,
                                            __half* __restrict__ feat_s,
                                            const int* __restrict__ batch,
                                            int* __restrict__ cnt,
                                            int2* __restrict__ idx2) {
    if (blockIdx.x < PREP_TOHALF_BLOCKS) {
        int i = (blockIdx.x * 256 + threadIdx.x) * 8;   // flat f32 index
        int n   = i >> 6;        // node
        int f0  = i & 63;
        int s   = f0 >> 4;       // slice
        int off = f0 & 15;       // 0 or 8 within slice
        float4 a = *(const float4*)(feat + i);
        float4 b = *(const float4*)(feat + i + 4);
        uint4 o;
        o.x = __builtin_bit_cast(unsigned int, __floats2half2_rn(a.x, a.y));
        o.y = __builtin_bit_cast(unsigned int, __floats2half2_rn(a.z, a.w));
        o.z = __builtin_bit_cast(unsigned int, __floats2half2_rn(b.x, b.y));
        o.w = __builtin_bit_cast(unsigned int, __floats2half2_rn(b.z, b.w));
        *(uint4*)(feat_s + (s * N_NODES + n) * SLICE_F + off) = o;
    } else {
        int b = (blockIdx.x - PREP_TOHALF_BLOCKS) * 256 + threadIdx.x;  // 0..BATCHSZ-1
        int4 br = ((const int4*)batch)[b];
        int p0 = atomicAdd(&cnt[br.x], 1);
        int p1 = atomicAdd(&cnt[br.y], 1);
        int p2 = atomicAdd(&cnt[br.z], 1);
        int p3 = atomicAdd(&cnt[br.w], 1);
        if (p0 < SRC_PER_NODE) idx2[br.x * SRC_PER_NODE + p0] = make_int2(br.y | (br.z << 16), br.w);
        if (p1 < SRC_PER_NODE) idx2[br.y * SRC_PER_NODE + p1] = make_int2(br.x | (br.z << 16), br.w);
        if (p2 < SRC_PER_NODE) idx2[br.z * SRC_PER_NODE + p2] = make_int2(br.x | (br.y << 16), br.w);
        if (p3 < SRC_PER_NODE) idx2[br.w * SRC_PER_NODE + p3] = make_int2(br.x | (br.y << 16), br.z);
    }
}

// ---- Pass 2 v3: 8 feats/lane, native packed-fp16 vectors, zero shuffles ----
// Block = 4 waves; wave = 32 node-slices. grp = lane>>1 picks node, fp = lane&1
// picks which 8-feat half of the 16-half slice row (16B uint4 loads).
// slice = blockIdx&3 (XCD-affine). Per source: 3 gathered uint4 + 4 heads x
// (mul+fma+fma+max) on h8 vectors -> pure v_pk_fma_f16 / v_pk_max_f16.
__global__ __launch_bounds__(256) void gat_agg_v3(const __half* __restrict__ feat_s,
                                                  const float* __restrict__ att,
                                                  const int2* __restrict__ idx2,
                                                  float* __restrict__ out) {
    const int lane  = threadIdx.x & 63;
    const int wave  = threadIdx.x >> 6;
    const int grp   = lane >> 1;    // node-slice within wave (0..31)
    const int fp    = lane & 1;     // 8-feat half of the slice row
    const int slice = blockIdx.x & 3;
    const int t     = (blockIdx.x >> 2) * 128 + wave * 32 + grp;

    // this lane's 8-feat base inside slice plane (rows are 32B, lane offset 16B)
    const __half* lslice = feat_s + (size_t)slice * (N_NODES * SLICE_F) + fp * 8;

    _Float16 w[N_HEADS][3];
    #pragma unroll
    for (int a = 0; a < N_HEADS; ++a)
        #pragma unroll
        for (int k = 0; k < 3; ++k)
            w[a][k] = (_Float16)att[a * 3 + k];

    h8 m0 = (h8)(_Float16)(-65504.0f);   // splat; below any attainable mix value
    h8 m1 = m0, m2 = m0, m3 = m0;

    const int2* ip = idx2 + (size_t)t * SRC_PER_NODE;
    #pragma unroll
    for (int s = 0; s < SRC_PER_NODE; ++s) {
        int2 nb = ip[s];                        // lane pair shares; 256B/wave, L1-hot
        unsigned n0 = nb.x & 0xffffu;
        unsigned n1 = ((unsigned)nb.x) >> 16;
        unsigned n2 = nb.y & 0xffffu;
        h8 f0 = __builtin_bit_cast(h8, *(const uint4*)(lslice + n0 * SLICE_F));
        h8 f1 = __builtin_bit_cast(h8, *(const uint4*)(lslice + n1 * SLICE_F));
        h8 f2 = __builtin_bit_cast(h8, *(const uint4*)(lslice + n2 * SLICE_F));
        m0 = __builtin_elementwise_max(m0, f0 * w[0][0] + f1 * w[0][1] + f2 * w[0][2]);
        m1 = __builtin_elementwise_max(m1, f0 * w[1][0] + f1 * w[1][1] + f2 * w[1][2]);
        m2 = __builtin_elementwise_max(m2, f0 * w[2][0] + f1 * w[2][1] + f2 * w[2][2]);
        m3 = __builtin_elementwise_max(m3, f0 * w[3][0] + f1 * w[3][1] + f2 * w[3][2]);
    }

    h8 sf = __builtin_bit_cast(h8, *(const uint4*)(lslice + (unsigned)t * SLICE_F));
    float* ob = out + (size_t)t * (N_HEADS * N_FEAT) + slice * SLICE_F + 8 * fp;

    #define EMIT(A, M) {                                                       \
        h8 oh = sf + (M);                                                      \
        oh = __builtin_elementwise_max(oh, oh * (_Float16)ALPHA);              \
        f32x8 of = __builtin_convertvector(oh, f32x8);                         \
        f32x4 lo = {of[0], of[1], of[2], of[3]};                               \
        f32x4 hi = {of[4], of[5], of[6], of[7]};                               \
        __builtin_nontemporal_store(lo, (f32x4*)(ob + (A) * N_FEAT));          \
        __builtin_nontemporal_store(hi, (f32x4*)(ob + (A) * N_FEAT + 4));      \
    }
    EMIT(0, m0); EMIT(1, m1); EMIT(2, m2); EMIT(3, m3);
    #undef EMIT
}

extern "C" void kernel_launch(void* const* d_in, const int* in_sizes, int n_in,
                              void* d_out, int out_size, void* d_ws, size_t ws_size,
                              hipStream_t stream) {
    const int*   batch = (const int*)d_in[0];    // [BATCHSZ, 4] int32
    const float* feat  = (const float*)d_in[1];  // [N_NODES, N_FEAT] f32
    const float* att   = (const float*)d_in[2];  // [N_HEADS, 3] f32
    float* out = (float*)d_out;                  // [N_NODES, 256] f32

    char* ws = (char*)d_ws;
    int*    cnt    = (int*)ws;                                        // 256 KB
    int2*   idx2   = (int2*)(ws + N_NODES * sizeof(int));             // 4 MB
    __half* feat_s = (__half*)(ws + N_NODES * sizeof(int)
                                  + N_NODES * SRC_PER_NODE * sizeof(int2));  // 8 MB

    hipMemsetAsync(cnt, 0, N_NODES * sizeof(int), stream);
    prep<<<PREP_TOHALF_BLOCKS + PREP_BUILD_BLOCKS, 256, 0, stream>>>(feat, feat_s, batch, cnt, idx2);
    gat_agg_v3<<<(N_NODES / 128) * NSLICE, 256, 0, stream>>>(feat_s, att, idx2, out);
}